// Round 4
// baseline (2639.655 us; speedup 1.0000x reference)
//
#include <hip/hip_runtime.h>
#include <hip/hip_bf16.h>
#include <stdint.h>

// Leaky RNN: v_t = 0.9 v_{t-1} + 0.1 (W_hid fr_{t-1} + b_hid + u_t), fr = relu(v)
// Phase A: u_proj (fp32 tiled GEMM) written into d_out in place.
// Phase B: persistent 64-WG scan with n-MAJOR state layout:
//   mfma(W_frag, fr_frag) -> D[row=n_local][col=m], so each thread's 4 acc
//   regs are 4 k-consecutive elements of next step's fr = exactly one 8B
//   exchange packet. No LDS transpose, no per-step barriers. Exchange via
//   SYSTEM-scope relaxed 8B atomics (sc0+sc1 -> L2 bypass, meet at IC).
//   Self-validating: fr>=0, so all 4 sign bits carry a step-parity tag;
//   consumers poll their own fragment loads until every packet matches.

#define SEQ   1024
#define BATCH 64
#define INDIM 128
#define HID   512
#define HG    16   // hid groups (k-chunks of 32)
#define BGN   4    // batch groups of 16

typedef __attribute__((ext_vector_type(8))) short   short8;
typedef __attribute__((ext_vector_type(4))) float   floatx4;
typedef unsigned long long ull;

__device__ __forceinline__ unsigned short f2bf(float x) {
  union { float f; unsigned int u; } v; v.f = x;
  unsigned int r = v.u + 0x7fffu + ((v.u >> 16) & 1u);  // RNE
  return (unsigned short)(r >> 16);
}
__device__ __forceinline__ ull pack4(unsigned short a, unsigned short b,
                                     unsigned short c, unsigned short d) {
  return (ull)a | ((ull)b << 16) | ((ull)c << 32) | ((ull)d << 48);
}

// ---------------- Phase A: u_proj = input @ W_in^T + b_in  (fp32) -----------
#define TA_SB 64
#define TA_H  128
#define TA_K  64
#define APAD  65

__global__ __launch_bounds__(256) void uproj_kernel(
    const float* __restrict__ inp, const float* __restrict__ Win,
    const float* __restrict__ bin, float* __restrict__ out)
{
  __shared__ float sIn[TA_SB * APAD];
  __shared__ float sW [TA_H  * APAD];
  const int tid = threadIdx.x;
  const int sb0 = (blockIdx.x >> 2) * TA_SB;
  const int h0  = (blockIdx.x & 3) * TA_H;
  const int tx = tid & 15, ty = tid >> 4;

  float acc[4][8];
  #pragma unroll
  for (int i = 0; i < 4; ++i)
    #pragma unroll
    for (int j = 0; j < 8; ++j) acc[i][j] = 0.f;

  for (int kt = 0; kt < INDIM / TA_K; ++kt) {
    #pragma unroll
    for (int p = 0; p < 4; ++p) {
      int idx = tid + 256 * p;
      int row = idx >> 4, c4 = (idx & 15) << 2;
      const float4 v = *(const float4*)(inp + (size_t)(sb0 + row) * INDIM + kt * TA_K + c4);
      float* d = sIn + row * APAD + c4;
      d[0] = v.x; d[1] = v.y; d[2] = v.z; d[3] = v.w;
    }
    #pragma unroll
    for (int p = 0; p < 8; ++p) {
      int idx = tid + 256 * p;
      int row = idx >> 4, c4 = (idx & 15) << 2;
      const float4 v = *(const float4*)(Win + (size_t)(h0 + row) * INDIM + kt * TA_K + c4);
      float* d = sW + row * APAD + c4;
      d[0] = v.x; d[1] = v.y; d[2] = v.z; d[3] = v.w;
    }
    __syncthreads();

    for (int k = 0; k < TA_K; ++k) {
      float a[4], b[8];
      #pragma unroll
      for (int i = 0; i < 4; ++i) a[i] = sIn[(ty + 16 * i) * APAD + k];
      #pragma unroll
      for (int j = 0; j < 8; ++j) b[j] = sW[(tx + 16 * j) * APAD + k];
      #pragma unroll
      for (int i = 0; i < 4; ++i)
        #pragma unroll
        for (int j = 0; j < 8; ++j) acc[i][j] = fmaf(a[i], b[j], acc[i][j]);
    }
    __syncthreads();
  }

  #pragma unroll
  for (int j = 0; j < 8; ++j) {
    float bb = bin[h0 + tx + 16 * j];
    #pragma unroll
    for (int i = 0; i < 4; ++i)
      out[(size_t)(sb0 + ty + 16 * i) * HID + h0 + tx + 16 * j] = acc[i][j] + bb;
  }
}

// ---------------- Phase B: persistent sequential scan -----------------------
// 64 WGs = 4 bg (M=16) x 16 hg (N=32). Wave w of a WG owns n-tile
// [h0 + w*16, h0 + w*16 + 16). frA: [slot=2][bg=4][kk=16][lane=64][2 ull].
__global__ __launch_bounds__(128) void scan_kernel(
    const float* __restrict__ Whid, const float* __restrict__ bhid,
    float* __restrict__ uo,      // d_out: u_proj in, fr out (in place)
    ull* __restrict__ frA)
{
  const int tid  = threadIdx.x;
  const int lane = tid & 63;
  const int wave = tid >> 6;
  const int bg = blockIdx.x >> 4;
  const int hg = blockIdx.x & 15;
  const int b0 = bg * 16;
  const int h0 = hg * 32;

  const int m   = lane & 15;                 // batch row (D col)
  const int q   = lane >> 4;                 // quad 0..3
  const int nb  = wave * 16 + q * 4;         // n-local base of my 4 acc regs
  const int ng  = h0 + nb;                   // global hid col base

  // ---- one-time: W_hid A-fragments into registers (bf16) ------------------
  // ww[kk]: A[row=n = h0+wave*16+(lane&15)][k = kk*32+(lane>>4)*8+j]
  short8 ww[HG];
  {
    const float* wrow = Whid + (size_t)(h0 + wave * 16 + m) * HID + q * 8;
    #pragma unroll
    for (int kk = 0; kk < HG; ++kk) {
      const float4 a = *(const float4*)(wrow + kk * 32);
      const float4 b = *(const float4*)(wrow + kk * 32 + 4);
      union { unsigned short s[8]; short8 v; } u;
      u.s[0] = f2bf(a.x); u.s[1] = f2bf(a.y); u.s[2] = f2bf(a.z); u.s[3] = f2bf(a.w);
      u.s[4] = f2bf(b.x); u.s[5] = f2bf(b.y); u.s[6] = f2bf(b.z); u.s[7] = f2bf(b.w);
      ww[kk] = u.v;
    }
  }

  // bias for my 4 n (consecutive)
  const float4 bias = *(const float4*)(bhid + ng);

  // publish destination: packet (kk=hg, lane' = m + 16*(nb>>3), half = (nb>>2)&1)
  ull* const pub = frA;  // indexed per step below
  const int pml  = m + 16 * ((nb >> 3) & 3);
  const int phh  = (nb >> 2) & 1;

  const ull MASKT = 0x8000800080008000ull;
  floatx4 v = {0.f, 0.f, 0.f, 0.f};
  const float OMA = 0.9f, AL = 0.1f;

  for (int t = 0; t < SEQ; ++t) {
    // Prefetch u_t: 4 consecutive hid for my batch row -> one float4.
    const float4 uu = *(const float4*)(uo + ((size_t)t * BATCH + b0 + m) * HID + ng);

    floatx4 acc[4];
    #pragma unroll
    for (int j = 0; j < 4; ++j) acc[j] = (floatx4){0.f, 0.f, 0.f, 0.f};

    if (t > 0) {
      const int slot = (t - 1) & 1;
      const ull expv = (((t - 1) >> 1) & 1) ? MASKT : 0ull;
      const ull* ap = frA + (size_t)(slot * BGN + bg) * HG * 128 + (size_t)lane * 2;
      ull lo[HG], hi[HG];
      for (;;) {
        int ok = 1;
        #pragma unroll
        for (int kk = 0; kk < HG; ++kk) {
          lo[kk] = __hip_atomic_load(ap + (size_t)kk * 128,
                                     __ATOMIC_RELAXED, __HIP_MEMORY_SCOPE_SYSTEM);
          hi[kk] = __hip_atomic_load(ap + (size_t)kk * 128 + 1,
                                     __ATOMIC_RELAXED, __HIP_MEMORY_SCOPE_SYSTEM);
          ok &= (int)(((lo[kk] & MASKT) == expv) & ((hi[kk] & MASKT) == expv));
        }
        if (__all(ok)) break;
      }
      #pragma unroll
      for (int kk = 0; kk < HG; ++kk) {
        union { ull u[2]; short8 s; } af;
        af.u[0] = lo[kk] & ~MASKT;
        af.u[1] = hi[kk] & ~MASKT;
        // operand swap: D[row=n_local][col=m] = sum_k W[n][k] * fr[m][k]
        acc[kk & 3] = __builtin_amdgcn_mfma_f32_16x16x32_bf16(ww[kk], af.s,
                                                              acc[kk & 3], 0, 0, 0);
      }
    }

    float fr[4];
    fr[0] = 0.f; fr[1] = 0.f; fr[2] = 0.f; fr[3] = 0.f;
    {
      const float ub[4] = {uu.x, uu.y, uu.z, uu.w};
      const float bb[4] = {bias.x, bias.y, bias.z, bias.w};
      #pragma unroll
      for (int r = 0; r < 4; ++r) {
        float s = acc[0][r] + acc[1][r] + acc[2][r] + acc[3][r];
        v[r] = OMA * v[r] + AL * (s + bb[r] + ub[r]);
        fr[r] = fmaxf(v[r], 0.f);
      }
    }

    // ---- publish: my 4 regs ARE one A-fragment packet. Tag + one store ----
    {
      ull pk = pack4(f2bf(fr[0]), f2bf(fr[1]), f2bf(fr[2]), f2bf(fr[3]));
      if ((t >> 1) & 1) pk |= MASKT;
      ull* dst = pub + (size_t)(((t & 1) * BGN + bg) * HG + hg) * 128
                     + (size_t)pml * 2 + phh;
      __hip_atomic_store(dst, pk, __ATOMIC_RELAXED, __HIP_MEMORY_SCOPE_SYSTEM);
    }

    // fp32 output: 4 consecutive floats -> one dwordx4 (off critical path)
    {
      float4 o; o.x = fr[0]; o.y = fr[1]; o.z = fr[2]; o.w = fr[3];
      *(float4*)(uo + ((size_t)t * BATCH + b0 + m) * HID + ng) = o;
    }
  }
}

// ---------------------------------------------------------------------------
extern "C" void kernel_launch(void* const* d_in, const int* in_sizes, int n_in,
                              void* d_out, int out_size, void* d_ws, size_t ws_size,
                              hipStream_t stream) {
  const float* inp  = (const float*)d_in[0];
  const float* Win  = (const float*)d_in[1];
  const float* bin  = (const float*)d_in[2];
  const float* Whid = (const float*)d_in[3];
  const float* bhid = (const float*)d_in[4];
  float* out = (float*)d_out;

  ull* frA = (ull*)d_ws;   // 128 KB; 0xAA poison has sign=1 => invalid vs tag 0

  uproj_kernel<<<dim3((65536 / TA_SB) * (HID / TA_H)), dim3(256), 0, stream>>>(
      inp, Win, bin, out);
  scan_kernel<<<dim3(BGN * HG), dim3(128), 0, stream>>>(
      Whid, bhid, out, frA);
}